// Round 6
// baseline (1231.548 us; speedup 1.0000x reference)
//
#include <hip/hip_runtime.h>
#include <stdint.h>

#define F_IN 512
#define HDIM 128
#define CDIM 16
#define KHOPS 10

#define NBMAX 1024      // max coarse buckets (supports N <= 262144)
#define CSTR 16         // ccur padding stride (ints) to kill same-line atomic contention
#define CHUNK 8192      // edges per k_part block
#define CH2 32768       // edges per k_ccount block

typedef __bf16 bf16x8 __attribute__((ext_vector_type(8)));
typedef float f32x4 __attribute__((ext_vector_type(4)));

typedef __attribute__((address_space(3))) unsigned int lds_uint;
typedef const __attribute__((address_space(1))) unsigned int g_uint;

__device__ __forceinline__ void dma16(const void* g, void* l) {
    __builtin_amdgcn_global_load_lds((g_uint*)g, (lds_uint*)l, 16, 0, 0);
}

__device__ __forceinline__ unsigned short f2bf(float f) {
    unsigned int u = __float_as_uint(f);
    u += 0x7FFFu + ((u >> 16) & 1u);
    return (unsigned short)(u >> 16);
}

__device__ __forceinline__ bf16x8 ld_bf8(const unsigned short* p) {
    uint4 u = *reinterpret_cast<const uint4*>(p);
    return __builtin_bit_cast(bf16x8, u);
}

// ---------------- CSC build ----------------
// coarse-first pipeline: coarse hist (LDS) -> coarse scan -> coarse partition ->
// per-bucket fused fine count/scan/scatter + local degree-sort (perm).

// coarse histogram: LDS-privatized, one global atomic per bucket per block
__global__ __launch_bounds__(256) void k_ccount(const int* __restrict__ eidx,
                                                int* __restrict__ ccnt, int E) {
    __shared__ int lh[NBMAX];
    int t = threadIdx.x;
    int base = blockIdx.x * CH2;
    int lim = E - base; if (lim > CH2) lim = CH2;
    for (int i = t; i < NBMAX; i += 256) lh[i] = 0;
    __syncthreads();
    for (int j = t; j < lim; j += 256)
        atomicAdd(&lh[eidx[(size_t)E + base + j] >> 8], 1);
    __syncthreads();
    for (int i = t; i < NBMAX; i += 256) {
        int v = lh[i];
        if (v) atomicAdd(&ccnt[i], v);
    }
}

// scan 1024 coarse counts -> coffs[0..1024]; seed ccur
__global__ void k_cscan(const int* __restrict__ ccnt, int* __restrict__ coffs,
                        int* __restrict__ ccur, int nbuk) {
    __shared__ int sh[256];
    int t = threadIdx.x;
    int i0 = t * 4;
    int v0 = ccnt[i0 + 0], v1 = ccnt[i0 + 1], v2 = ccnt[i0 + 2], v3 = ccnt[i0 + 3];
    int s = v0 + v1 + v2 + v3;
    sh[t] = s;
    __syncthreads();
    for (int d = 1; d < 256; d <<= 1) {
        int x = (t >= d) ? sh[t - d] : 0;
        __syncthreads();
        sh[t] += x;
        __syncthreads();
    }
    int e0 = sh[t] - s;
    int e1 = e0 + v0, e2 = e1 + v1, e3 = e2 + v2;
    coffs[i0 + 0] = e0;
    coffs[i0 + 1] = e1;
    coffs[i0 + 2] = e2;
    coffs[i0 + 3] = e3;
    if (t == 255) coffs[1024] = e3 + v3;
    if (i0 + 0 < nbuk) ccur[(i0 + 0) * CSTR] = e0;
    if (i0 + 1 < nbuk) ccur[(i0 + 1) * CSTR] = e1;
    if (i0 + 2 < nbuk) ccur[(i0 + 2) * CSTR] = e2;
    if (i0 + 3 < nbuk) ccur[(i0 + 3) * CSTR] = e3;
}

// phase A: coarse partition edges by col>>8 into cedges (row,col), localized writes
__global__ __launch_bounds__(256) void k_part(
    const int* __restrict__ eidx, int* __restrict__ ccur,
    uint2* __restrict__ cedges, int E)
{
    __shared__ int lh[NBMAX];     // histogram
    __shared__ int loff[NBMAX];   // local exclusive offsets (immutable)
    __shared__ int lcur[NBMAX];   // local cursors
    __shared__ int gbase[NBMAX];  // reserved global bases
    __shared__ int sh[256];

    int t = threadIdx.x;
    int base = blockIdx.x * CHUNK;
    int lim = E - base; if (lim > CHUNK) lim = CHUNK;

    for (int i = t; i < NBMAX; i += 256) lh[i] = 0;
    __syncthreads();

    // sweep 1: histogram coarse buckets
    for (int j = t; j < lim; j += 256) {
        int c = eidx[(size_t)E + base + j];
        atomicAdd(&lh[c >> 8], 1);
    }
    __syncthreads();

    // scan 1024 entries (4/thread)
    int i0 = t * 4;
    int v0 = lh[i0 + 0], v1 = lh[i0 + 1], v2 = lh[i0 + 2], v3 = lh[i0 + 3];
    int s = v0 + v1 + v2 + v3;
    sh[t] = s;
    __syncthreads();
    for (int d = 1; d < 256; d <<= 1) {
        int x = (t >= d) ? sh[t - d] : 0;
        __syncthreads();
        sh[t] += x;
        __syncthreads();
    }
    int excl = sh[t] - s;
    loff[i0 + 0] = excl; lcur[i0 + 0] = excl;
    gbase[i0 + 0] = v0 ? atomicAdd(&ccur[(i0 + 0) * CSTR], v0) : 0;
    excl += v0;
    loff[i0 + 1] = excl; lcur[i0 + 1] = excl;
    gbase[i0 + 1] = v1 ? atomicAdd(&ccur[(i0 + 1) * CSTR], v1) : 0;
    excl += v1;
    loff[i0 + 2] = excl; lcur[i0 + 2] = excl;
    gbase[i0 + 2] = v2 ? atomicAdd(&ccur[(i0 + 2) * CSTR], v2) : 0;
    excl += v2;
    loff[i0 + 3] = excl; lcur[i0 + 3] = excl;
    gbase[i0 + 3] = v3 ? atomicAdd(&ccur[(i0 + 3) * CSTR], v3) : 0;
    __syncthreads();

    // sweep 2: place edges; per-bucket runs land contiguous in cedges
    for (int j = t; j < lim; j += 256) {
        int r = eidx[base + j];
        int c = eidx[(size_t)E + base + j];
        int b = c >> 8;
        int lp = atomicAdd(&lcur[b], 1);
        int gpos = gbase[b] + (lp - loff[b]);
        uint2 u; u.x = (unsigned)r; u.y = (unsigned)c;
        cedges[gpos] = u;
    }
}

// fused fine phase: per coarse bucket (256 cols):
//  1) LDS degree count  2) scan -> cnt/dis/offs  3) LDS counting-sort by degree
//     -> perm (degree-balanced hop scheduling)  4) scatter source indices.
// Only the SOURCE index is stored (4 B/edge): norm is factorized into the
// y = dis[v]*x[v] exchange representation used by the hop kernel.
__global__ __launch_bounds__(256) void k_fine(
    const uint2* __restrict__ cedges, const int* __restrict__ coffs,
    int* __restrict__ cnt, float* __restrict__ dis, int* __restrict__ offs,
    int* __restrict__ srcs, int* __restrict__ perm, int N)
{
    __shared__ int lh[256];
    __shared__ int sh[256];
    __shared__ int dh[512];
    __shared__ int lcur[256];
    int b = blockIdx.x;
    int t = threadIdx.x;
    int col0 = b << 8;
    int segs = coffs[b];
    int sege = coffs[b + 1];
    lh[t] = 0; dh[t] = 0; dh[256 + t] = 0;
    __syncthreads();
    for (int j = segs + t; j < sege; j += 256)
        atomicAdd(&lh[(int)cedges[j].y - col0], 1);
    __syncthreads();
    int c = lh[t];
    // scan per-col counts -> edge offsets
    sh[t] = c;
    __syncthreads();
    for (int d = 1; d < 256; d <<= 1) {
        int x = (t >= d) ? sh[t - d] : 0;
        __syncthreads();
        sh[t] += x;
        __syncthreads();
    }
    int excl = sh[t] - c;
    int col = col0 + t;
    int key = c < 511 ? c : 511;
    if (col < N) {
        cnt[col] = c;
        dis[col] = rsqrtf((float)(c + 1));
        offs[col] = segs + excl;
        lcur[t] = segs + excl;
        atomicAdd(&dh[key], 1);
    }
    __syncthreads();
    // scan 512 degree bins (2 per thread)
    int b0 = dh[2 * t], b1 = dh[2 * t + 1];
    int s2 = b0 + b1;
    sh[t] = s2;
    __syncthreads();
    for (int d = 1; d < 256; d <<= 1) {
        int x = (t >= d) ? sh[t - d] : 0;
        __syncthreads();
        sh[t] += x;
        __syncthreads();
    }
    int e2 = sh[t] - s2;
    dh[2 * t] = e2;
    dh[2 * t + 1] = e2 + b0;
    __syncthreads();
    if (col < N) {
        int rank = atomicAdd(&dh[key], 1);
        perm[col0 + rank] = col;
    }
    // scatter source indices (cedges segment is L2-hot from sweep 1)
    for (int j = segs + t; j < sege; j += 256) {
        uint2 e = cedges[j];
        int li = (int)e.y - col0;
        int pos = atomicAdd(&lcur[li], 1);
        srcs[pos] = (int)e.x;
    }
}

// ---------------- x f32 -> bf16 (once) ----------------

__global__ void k_xbf(const float* __restrict__ x, unsigned short* __restrict__ xbf) {
    size_t i = (size_t)blockIdx.x * 2048 + (size_t)threadIdx.x * 8;
    float4 a = *reinterpret_cast<const float4*>(&x[i]);
    float4 b = *reinterpret_cast<const float4*>(&x[i + 4]);
    unsigned short s[8];
    s[0] = f2bf(a.x); s[1] = f2bf(a.y); s[2] = f2bf(a.z); s[3] = f2bf(a.w);
    s[4] = f2bf(b.x); s[5] = f2bf(b.y); s[6] = f2bf(b.z); s[7] = f2bf(b.w);
    *reinterpret_cast<uint4*>(&xbf[i]) = *reinterpret_cast<uint4*>(s);
}

// ---------------- W1 transpose+convert: [512][128] f32 -> [128][512] bf16 ----------------

__global__ void k_w1t(const float* __restrict__ W1l, const float* __restrict__ W1g,
                      unsigned short* __restrict__ W1Tl, unsigned short* __restrict__ W1Tg) {
    const float* W1 = blockIdx.y ? W1g : W1l;
    unsigned short* W1T = blockIdx.y ? W1Tg : W1Tl;
    int idx = blockIdx.x * 256 + threadIdx.x;
    int n = idx >> 6;
    int k0 = (idx & 63) * 8;
    unsigned short tmp[8];
    for (int j = 0; j < 8; j++)
        tmp[j] = f2bf(W1[(size_t)(k0 + j) * HDIM + n]);
    *reinterpret_cast<uint4*>(&W1T[(size_t)n * F_IN + k0]) = *reinterpret_cast<uint4*>(tmp);
}

// ---------------- fused GEMM: h1 = relu(x@W1+b1); h2 = h1@W2+b2 ----------------
// grid (ceil(N/128), 2), 256 threads. blockIdx.y = branch.
// LDS 34816 B union: K-loop { As 16K swizzled | Bs 16K swizzled } ; epilogue Hs [128][136] bf16.
// Epilogue 2 seeds propagation state in channel-contiguous [N][32] layout:
//   y0[node*32 + br*16 + m16] = dis[node]*h2,  hid[...] = temp[0]*h2

__global__ __launch_bounds__(256, 4) void k_gemm(
    const unsigned short* __restrict__ xbf,
    const unsigned short* __restrict__ W1Tl, const float* __restrict__ b1l,
    const float* __restrict__ W2l, const float* __restrict__ b2l, const float* __restrict__ tl,
    const unsigned short* __restrict__ W1Tg, const float* __restrict__ b1g,
    const float* __restrict__ W2g, const float* __restrict__ b2g, const float* __restrict__ tg,
    const float* __restrict__ dis,
    float* __restrict__ h1l, float* __restrict__ h1g,
    float* __restrict__ y0, float* __restrict__ hidb, int nNode)
{
    const int br = blockIdx.y;
    const unsigned short* w1t = br ? W1Tg : W1Tl;
    const float* B1 = br ? b1g : b1l;
    const float* W2 = br ? W2g : W2l;
    const float* B2 = br ? b2g : b2l;
    const float* tp = br ? tg : tl;
    float* h1 = br ? h1g : h1l;

    __shared__ __align__(16) unsigned short sm[17408];   // 34816 B
    unsigned short* As = sm;            // slots 0..1023   (rows 0..127 x 8 slots)
    unsigned short* Bs = sm + 8192;     // slots 0..1023
    unsigned short* Hs = sm;            // [128][136] epilogue

    const int t = threadIdx.x;
    const int lane = t & 63;
    const int w = t >> 6;
    const int row0 = blockIdx.x * 128;

    f32x4 acc[2][8];
    for (int i = 0; i < 2; i++)
        for (int j = 0; j < 8; j++)
            acc[i][j] = f32x4{0.f, 0.f, 0.f, 0.f};

    const int m16 = lane & 15;
    const int q = lane >> 4;

    for (int k0 = 0; k0 < F_IN; k0 += 64) {
        #pragma unroll
        for (int j = 0; j < 4; j++) {
            int S0 = w * 256 + j * 64;
            int S = S0 + lane;
            int row = S >> 3;
            int cb = (S & 7) ^ (row & 7);
            dma16(&xbf[(size_t)(row0 + row) * F_IN + k0 + cb * 8], &As[(size_t)S0 * 8]);
        }
        #pragma unroll
        for (int j = 0; j < 4; j++) {
            int S0 = w * 256 + j * 64;
            int S = S0 + lane;
            int n = S >> 3;
            int cb = (S & 7) ^ (n & 7);
            dma16(&w1t[(size_t)n * F_IN + k0 + cb * 8], &Bs[(size_t)S0 * 8]);
        }
        __syncthreads();

        #pragma unroll
        for (int ksub = 0; ksub < 2; ksub++) {
            bf16x8 bf[8];
            #pragma unroll
            for (int ns = 0; ns < 8; ns++) {
                int n = ns * 16 + m16;
                int slot = n * 8 + ((ksub * 4 + q) ^ (n & 7));
                bf[ns] = ld_bf8(&Bs[slot * 8]);
            }
            bf16x8 af[2];
            #pragma unroll
            for (int ms = 0; ms < 2; ms++) {
                int row = w * 32 + ms * 16 + m16;
                int slot = row * 8 + ((ksub * 4 + q) ^ (row & 7));
                af[ms] = ld_bf8(&As[slot * 8]);
            }
            #pragma unroll
            for (int ns = 0; ns < 8; ns++)
                #pragma unroll
                for (int ms = 0; ms < 2; ms++)
                    acc[ms][ns] = __builtin_amdgcn_mfma_f32_16x16x32_bf16(af[ms], bf[ns], acc[ms][ns], 0, 0, 0);
        }
        __syncthreads();
    }

    // epilogue 1: h1 = relu(acc + b1); write global + stash bf16 in LDS
    #pragma unroll
    for (int ms = 0; ms < 2; ms++) {
        #pragma unroll
        for (int ns = 0; ns < 8; ns++) {
            int n = ns * 16 + m16;
            float bias = B1[n];
            #pragma unroll
            for (int r = 0; r < 4; r++) {
                int m = w * 32 + ms * 16 + q * 4 + r;
                float v = acc[ms][ns][r] + bias;
                v = v > 0.f ? v : 0.f;
                Hs[m * 136 + n] = f2bf(v);
                int node = row0 + m;
                if (node < nNode) h1[(size_t)node * HDIM + n] = v;
            }
        }
    }
    __syncthreads();

    // epilogue 2: h2 = h1 @ W2 + b2 via MFMA (N=16); seed y0 + hid.
    {
        float t0 = tp[0];
        float bias = B2[m16];
        #pragma unroll
        for (int mi = 0; mi < 2; mi++) {
            int mt = w * 2 + mi;
            f32x4 acc2 = f32x4{bias, bias, bias, bias};
            #pragma unroll
            for (int kb = 0; kb < 4; kb++) {
                bf16x8 hf = ld_bf8(&Hs[(mt * 16 + m16) * 136 + kb * 32 + q * 8]);
                unsigned short wtmp[8];
                #pragma unroll
                for (int j = 0; j < 8; j++)
                    wtmp[j] = f2bf(W2[(size_t)(kb * 32 + q * 8 + j) * CDIM + m16]);
                bf16x8 wf = ld_bf8(wtmp);
                acc2 = __builtin_amdgcn_mfma_f32_16x16x32_bf16(hf, wf, acc2, 0, 0, 0);
            }
            #pragma unroll
            for (int r = 0; r < 4; r++) {
                int node = row0 + mt * 16 + q * 4 + r;
                if (node < nNode) {
                    size_t idx = (size_t)node * 32 + (size_t)br * 16 + m16;
                    float val = acc2[r];
                    y0[idx] = dis[node] * val;
                    hidb[idx] = t0 * val;
                }
            }
        }
    }
}

// ---------------- propagation hop: 8 lanes/node x float4 channels ----------------
// block 256 = 32 nodes taken from the degree-sorted perm -> the 8 nodes of a
// wave have near-equal degree (no exec-mask divergence waste). The 8 lanes of
// a node read CONSECUTIVE 16 B of each gathered source row -> coalesced 128 B.
// y = dis*x representation: x' = d*(sum_src y[src] + y[v]); y' = d*x'.
// Last hop fuses hid finalization + log_softmax (classes of a branch live in
// 4 adjacent lanes; LSE via two __shfl_xor).

__global__ __launch_bounds__(256) void k_hop3(
    const float* __restrict__ yin, float* __restrict__ yout,
    float* __restrict__ hidb, const int* __restrict__ srcs,
    const int* __restrict__ offs, const int* __restrict__ cnt,
    const float* __restrict__ dis, const int* __restrict__ perm,
    const float* __restrict__ tl, const float* __restrict__ tg,
    float* __restrict__ h2l, float* __restrict__ pl,
    float* __restrict__ h2g, float* __restrict__ pg,
    int hop, int N, int last)
{
    int t = threadIdx.x;
    int vi = blockIdx.x * 32 + (t >> 3);
    int s = t & 7;
    int c4 = s * 4;
    if (vi >= N) return;
    int v = perm[vi];
    int off = offs[v];
    int m = cnt[v];
    float d = dis[v];
    size_t vbase = (size_t)v * 32 + c4;
    float4 acc = *reinterpret_cast<const float4*>(yin + vbase);   // self term y[v]
    const int* ep = srcs + off;
    int i = 0;
    for (; i + 8 <= m; i += 8) {
        int u[8];
        #pragma unroll
        for (int j = 0; j < 8; j++) u[j] = ep[i + j];
        float4 xs[8];
        #pragma unroll
        for (int j = 0; j < 8; j++)
            xs[j] = *reinterpret_cast<const float4*>(yin + (size_t)u[j] * 32 + c4);
        #pragma unroll
        for (int j = 0; j < 8; j++) {
            acc.x += xs[j].x; acc.y += xs[j].y;
            acc.z += xs[j].z; acc.w += xs[j].w;
        }
    }
    for (; i < m; i++) {
        float4 xs = *reinterpret_cast<const float4*>(yin + (size_t)ep[i] * 32 + c4);
        acc.x += xs.x; acc.y += xs.y; acc.z += xs.z; acc.w += xs.w;
    }
    float4 xn = make_float4(d * acc.x, d * acc.y, d * acc.z, d * acc.w);
    float gamma = (s < 4 ? tl : tg)[hop];
    float4 h = *reinterpret_cast<const float4*>(hidb + vbase);
    h.x = fmaf(gamma, xn.x, h.x);
    h.y = fmaf(gamma, xn.y, h.y);
    h.z = fmaf(gamma, xn.z, h.z);
    h.w = fmaf(gamma, xn.w, h.w);
    if (!last) {
        *reinterpret_cast<float4*>(hidb + vbase) = h;
        *reinterpret_cast<float4*>(yout + vbase) =
            make_float4(d * xn.x, d * xn.y, d * xn.z, d * xn.w);
    } else {
        // fused log_softmax over this branch's 16 classes (4 adjacent lanes)
        float mloc = fmaxf(fmaxf(h.x, h.y), fmaxf(h.z, h.w));
        mloc = fmaxf(mloc, __shfl_xor(mloc, 1));
        mloc = fmaxf(mloc, __shfl_xor(mloc, 2));
        float sl = __expf(h.x - mloc) + __expf(h.y - mloc) +
                   __expf(h.z - mloc) + __expf(h.w - mloc);
        sl += __shfl_xor(sl, 1);
        sl += __shfl_xor(sl, 2);
        float lse = mloc + __logf(sl);
        float* h2 = s < 4 ? h2l : h2g;
        float* pp = s < 4 ? pl : pg;
        size_t ob = (size_t)v * 16 + (size_t)(s & 3) * 4;
        *reinterpret_cast<float4*>(h2 + ob) = h;
        *reinterpret_cast<float4*>(pp + ob) =
            make_float4(h.x - lse, h.y - lse, h.z - lse, h.w - lse);
    }
}

// ---------------- launch ----------------

extern "C" void kernel_launch(void* const* d_in, const int* in_sizes, int n_in,
                              void* d_out, int out_size, void* d_ws, size_t ws_size,
                              hipStream_t stream)
{
    const float* x   = (const float*)d_in[0];
    const int*   eidx= (const int*)d_in[1];
    const float* W1l = (const float*)d_in[2];
    const float* b1l = (const float*)d_in[3];
    const float* W2l = (const float*)d_in[4];
    const float* b2l = (const float*)d_in[5];
    const float* tl  = (const float*)d_in[6];
    const float* W1g = (const float*)d_in[7];
    const float* b1g = (const float*)d_in[8];
    const float* W2g = (const float*)d_in[9];
    const float* b2g = (const float*)d_in[10];
    const float* tg  = (const float*)d_in[11];

    const int N = in_sizes[0] / F_IN;
    const int E = in_sizes[1] / 2;

    float* out = (float*)d_out;
    float* h1l = out;
    float* h2l = h1l + (size_t)N * HDIM;
    float* pl  = h2l + (size_t)N * CDIM;
    float* h1g = pl  + (size_t)N * CDIM;
    float* h2g = h1g + (size_t)N * HDIM;
    float* pg  = h2g + (size_t)N * CDIM;

    char* ws = (char*)d_ws;
    auto alloc = [&](size_t bytes) -> char* {
        char* p = ws;
        ws += (bytes + 1023) & ~(size_t)1023;
        return p;
    };
    int*   cnt      = (int*)alloc((size_t)N * 4);
    int*   offs     = (int*)alloc((size_t)N * 4);
    int*   perm     = (int*)alloc((size_t)(N + 256) * 4);
    int*   ccnt     = (int*)alloc((size_t)(NBMAX + 1) * 4);
    int*   coffs    = (int*)alloc((size_t)(NBMAX + 1) * 4);
    int*   ccur     = (int*)alloc((size_t)NBMAX * CSTR * 4);
    float* dis      = (float*)alloc((size_t)N * 4);
    int*   srcs     = (int*)alloc((size_t)E * 4);
    float* yA       = (float*)alloc((size_t)N * 32 * 4);   // [N][32] channel-contiguous
    float* yB       = (float*)alloc((size_t)N * 32 * 4);
    float* hidb     = (float*)alloc((size_t)N * 32 * 4);
    unsigned short* W1Tl = (unsigned short*)alloc((size_t)HDIM * F_IN * 2);
    unsigned short* W1Tg = (unsigned short*)alloc((size_t)HDIM * F_IN * 2);
    unsigned short* xbf  = (unsigned short*)alloc((size_t)(N + 256) * F_IN * 2);
    // coarse-partitioned (row,col) edges alias xbf: dead before k_xbf runs (same stream)
    uint2* cedges = (uint2*)xbf;

    hipMemsetAsync(ccnt, 0, (size_t)(NBMAX + 1) * 4, stream);

    int nbuk = (N + 255) / 256;

    k_ccount<<<(E + CH2 - 1) / CH2, 256, 0, stream>>>(eidx, ccnt, E);
    k_cscan<<<1, 256, 0, stream>>>(ccnt, coffs, ccur, nbuk);
    k_part<<<(E + CHUNK - 1) / CHUNK, 256, 0, stream>>>(eidx, ccur, cedges, E);
    k_fine<<<nbuk, 256, 0, stream>>>(cedges, coffs, cnt, dis, offs, srcs, perm, N);

    k_xbf<<<(int)(((size_t)N * F_IN) / 2048), 256, 0, stream>>>(x, xbf);
    dim3 gw(32, 2);
    k_w1t<<<gw, 256, 0, stream>>>(W1l, W1g, W1Tl, W1Tg);

    dim3 gg((N + 127) / 128, 2);
    k_gemm<<<gg, 256, 0, stream>>>(xbf, W1Tl, b1l, W2l, b2l, tl,
                                   W1Tg, b1g, W2g, b2g, tg, dis,
                                   h1l, h1g, yA, hidb, N);

    int gh = (N + 31) / 32;
    float* a = yA;
    float* b = yB;
    for (int k = 1; k <= KHOPS; k++) {
        k_hop3<<<gh, 256, 0, stream>>>(a, b, hidb, srcs, offs, cnt, dis, perm,
                                       tl, tg, h2l, pl, h2g, pg, k, N, k == KHOPS);
        float* tmp = a; a = b; b = tmp;
    }
}

// Round 7
// 976.002 us; speedup vs baseline: 1.2618x; 1.2618x over previous
//
#include <hip/hip_runtime.h>
#include <stdint.h>

#define F_IN 512
#define HDIM 128
#define CDIM 16
#define KHOPS 10

#define NBMAX 1024      // max coarse buckets (supports N <= 262144)
#define CSTR 16         // ccur padding stride (ints) to kill same-line atomic contention
#define CHUNK 8192      // edges per k_part block
#define CH2 32768       // edges per k_ccount block

typedef __bf16 bf16x8 __attribute__((ext_vector_type(8)));
typedef float f32x4 __attribute__((ext_vector_type(4)));

typedef __attribute__((address_space(3))) unsigned int lds_uint;
typedef const __attribute__((address_space(1))) unsigned int g_uint;

__device__ __forceinline__ void dma16(const void* g, void* l) {
    __builtin_amdgcn_global_load_lds((g_uint*)g, (lds_uint*)l, 16, 0, 0);
}

__device__ __forceinline__ unsigned short f2bf(float f) {
    unsigned int u = __float_as_uint(f);
    u += 0x7FFFu + ((u >> 16) & 1u);
    return (unsigned short)(u >> 16);
}

// unpack 4 bf16 (packed in uint2) -> 4 f32
__device__ __forceinline__ float4 bf4_to_f4(uint2 u) {
    return make_float4(__uint_as_float(u.x << 16),
                       __uint_as_float(u.x & 0xFFFF0000u),
                       __uint_as_float(u.y << 16),
                       __uint_as_float(u.y & 0xFFFF0000u));
}

// pack 4 f32 -> 4 bf16 (RNE) in uint2
__device__ __forceinline__ uint2 f4_to_bf4(float4 f) {
    uint2 u;
    u.x = (unsigned)f2bf(f.x) | ((unsigned)f2bf(f.y) << 16);
    u.y = (unsigned)f2bf(f.z) | ((unsigned)f2bf(f.w) << 16);
    return u;
}

__device__ __forceinline__ bf16x8 ld_bf8(const unsigned short* p) {
    uint4 u = *reinterpret_cast<const uint4*>(p);
    return __builtin_bit_cast(bf16x8, u);
}

// ---------------- CSC build ----------------
// coarse-first pipeline: coarse hist (LDS) -> coarse scan -> coarse partition ->
// per-bucket fine count/scan (LDS, no global atomics) -> per-bucket fine scatter.

// coarse histogram: LDS-privatized, one global atomic per bucket per block
__global__ __launch_bounds__(256) void k_ccount(const int* __restrict__ eidx,
                                                int* __restrict__ ccnt, int E) {
    __shared__ int lh[NBMAX];
    int t = threadIdx.x;
    int base = blockIdx.x * CH2;
    int lim = E - base; if (lim > CH2) lim = CH2;
    for (int i = t; i < NBMAX; i += 256) lh[i] = 0;
    __syncthreads();
    for (int j = t; j < lim; j += 256)
        atomicAdd(&lh[eidx[(size_t)E + base + j] >> 8], 1);
    __syncthreads();
    for (int i = t; i < NBMAX; i += 256) {
        int v = lh[i];
        if (v) atomicAdd(&ccnt[i], v);
    }
}

// scan 1024 coarse counts -> coffs[0..1024]; seed ccur
__global__ void k_cscan(const int* __restrict__ ccnt, int* __restrict__ coffs,
                        int* __restrict__ ccur, int nbuk) {
    __shared__ int sh[256];
    int t = threadIdx.x;
    int i0 = t * 4;
    int v0 = ccnt[i0 + 0], v1 = ccnt[i0 + 1], v2 = ccnt[i0 + 2], v3 = ccnt[i0 + 3];
    int s = v0 + v1 + v2 + v3;
    sh[t] = s;
    __syncthreads();
    for (int d = 1; d < 256; d <<= 1) {
        int x = (t >= d) ? sh[t - d] : 0;
        __syncthreads();
        sh[t] += x;
        __syncthreads();
    }
    int e0 = sh[t] - s;
    int e1 = e0 + v0, e2 = e1 + v1, e3 = e2 + v2;
    coffs[i0 + 0] = e0;
    coffs[i0 + 1] = e1;
    coffs[i0 + 2] = e2;
    coffs[i0 + 3] = e3;
    if (t == 255) coffs[1024] = e3 + v3;
    if (i0 + 0 < nbuk) ccur[(i0 + 0) * CSTR] = e0;
    if (i0 + 1 < nbuk) ccur[(i0 + 1) * CSTR] = e1;
    if (i0 + 2 < nbuk) ccur[(i0 + 2) * CSTR] = e2;
    if (i0 + 3 < nbuk) ccur[(i0 + 3) * CSTR] = e3;
}

// phase A: coarse partition edges by col>>8 into cedges (row,col), localized writes
__global__ __launch_bounds__(256) void k_part(
    const int* __restrict__ eidx, int* __restrict__ ccur,
    uint2* __restrict__ cedges, int E)
{
    __shared__ int lh[NBMAX];     // histogram
    __shared__ int loff[NBMAX];   // local exclusive offsets (immutable)
    __shared__ int lcur[NBMAX];   // local cursors
    __shared__ int gbase[NBMAX];  // reserved global bases
    __shared__ int sh[256];

    int t = threadIdx.x;
    int base = blockIdx.x * CHUNK;
    int lim = E - base; if (lim > CHUNK) lim = CHUNK;

    for (int i = t; i < NBMAX; i += 256) lh[i] = 0;
    __syncthreads();

    // sweep 1: histogram coarse buckets
    for (int j = t; j < lim; j += 256) {
        int c = eidx[(size_t)E + base + j];
        atomicAdd(&lh[c >> 8], 1);
    }
    __syncthreads();

    // scan 1024 entries (4/thread)
    int i0 = t * 4;
    int v0 = lh[i0 + 0], v1 = lh[i0 + 1], v2 = lh[i0 + 2], v3 = lh[i0 + 3];
    int s = v0 + v1 + v2 + v3;
    sh[t] = s;
    __syncthreads();
    for (int d = 1; d < 256; d <<= 1) {
        int x = (t >= d) ? sh[t - d] : 0;
        __syncthreads();
        sh[t] += x;
        __syncthreads();
    }
    int excl = sh[t] - s;
    loff[i0 + 0] = excl; lcur[i0 + 0] = excl;
    gbase[i0 + 0] = v0 ? atomicAdd(&ccur[(i0 + 0) * CSTR], v0) : 0;
    excl += v0;
    loff[i0 + 1] = excl; lcur[i0 + 1] = excl;
    gbase[i0 + 1] = v1 ? atomicAdd(&ccur[(i0 + 1) * CSTR], v1) : 0;
    excl += v1;
    loff[i0 + 2] = excl; lcur[i0 + 2] = excl;
    gbase[i0 + 2] = v2 ? atomicAdd(&ccur[(i0 + 2) * CSTR], v2) : 0;
    excl += v2;
    loff[i0 + 3] = excl; lcur[i0 + 3] = excl;
    gbase[i0 + 3] = v3 ? atomicAdd(&ccur[(i0 + 3) * CSTR], v3) : 0;
    __syncthreads();

    // sweep 2: place edges; per-bucket runs land contiguous in cedges
    for (int j = t; j < lim; j += 256) {
        int r = eidx[base + j];
        int c = eidx[(size_t)E + base + j];
        int b = c >> 8;
        int lp = atomicAdd(&lcur[b], 1);
        int gpos = gbase[b] + (lp - loff[b]);
        uint2 u; u.x = (unsigned)r; u.y = (unsigned)c;
        cedges[gpos] = u;
    }
}

// phase B1: per-bucket fine degree count (LDS), emit cnt/dis/offs — no global atomics
__global__ __launch_bounds__(256) void k_fineA(
    const uint2* __restrict__ cedges, const int* __restrict__ coffs,
    int* __restrict__ cnt, float* __restrict__ dis, int* __restrict__ offs, int N)
{
    __shared__ int lh[256];
    __shared__ int sh[256];
    int b = blockIdx.x;
    int t = threadIdx.x;
    int col0 = b << 8;
    int segs = coffs[b];
    int sege = coffs[b + 1];
    lh[t] = 0;
    __syncthreads();
    for (int j = segs + t; j < sege; j += 256)
        atomicAdd(&lh[(int)cedges[j].y - col0], 1);
    __syncthreads();
    int c = lh[t];
    sh[t] = c;
    __syncthreads();
    for (int d = 1; d < 256; d <<= 1) {
        int x = (t >= d) ? sh[t - d] : 0;
        __syncthreads();
        sh[t] += x;
        __syncthreads();
    }
    int excl = sh[t] - c;
    int col = col0 + t;
    if (col < N) {
        cnt[col] = c;
        dis[col] = rsqrtf((float)(c + 1));
        offs[col] = segs + excl;
    }
}

// phase B2: fine scatter within one coarse bucket (256 cols); LDS cursors.
// only the SOURCE index is stored (4 B/edge): norm is factorized into the
// y = dis[v]*x[v] exchange representation used by the hop kernel.
__global__ __launch_bounds__(256) void k_fineB(
    const uint2* __restrict__ cedges, const int* __restrict__ coffs,
    const int* __restrict__ offs, int* __restrict__ srcs, int N)
{
    __shared__ int lcur[256];
    int b = blockIdx.x;
    int col0 = b << 8;
    int t = threadIdx.x;
    int col = col0 + t;
    int segs = coffs[b];
    int sege = coffs[b + 1];
    if (col < N) lcur[t] = offs[col];
    __syncthreads();
    for (int j = segs + t; j < sege; j += 256) {
        uint2 e = cedges[j];
        int li = (int)e.y - col0;
        int pos = atomicAdd(&lcur[li], 1);
        srcs[pos] = (int)e.x;
    }
}

// ---------------- x f32 -> bf16 (once) ----------------

__global__ void k_xbf(const float* __restrict__ x, unsigned short* __restrict__ xbf) {
    size_t i = (size_t)blockIdx.x * 2048 + (size_t)threadIdx.x * 8;
    float4 a = *reinterpret_cast<const float4*>(&x[i]);
    float4 b = *reinterpret_cast<const float4*>(&x[i + 4]);
    unsigned short s[8];
    s[0] = f2bf(a.x); s[1] = f2bf(a.y); s[2] = f2bf(a.z); s[3] = f2bf(a.w);
    s[4] = f2bf(b.x); s[5] = f2bf(b.y); s[6] = f2bf(b.z); s[7] = f2bf(b.w);
    *reinterpret_cast<uint4*>(&xbf[i]) = *reinterpret_cast<uint4*>(s);
}

// ---------------- W1 transpose+convert: [512][128] f32 -> [128][512] bf16 ----------------

__global__ void k_w1t(const float* __restrict__ W1l, const float* __restrict__ W1g,
                      unsigned short* __restrict__ W1Tl, unsigned short* __restrict__ W1Tg) {
    const float* W1 = blockIdx.y ? W1g : W1l;
    unsigned short* W1T = blockIdx.y ? W1Tg : W1Tl;
    int idx = blockIdx.x * 256 + threadIdx.x;
    int n = idx >> 6;
    int k0 = (idx & 63) * 8;
    unsigned short tmp[8];
    for (int j = 0; j < 8; j++)
        tmp[j] = f2bf(W1[(size_t)(k0 + j) * HDIM + n]);
    *reinterpret_cast<uint4*>(&W1T[(size_t)n * F_IN + k0]) = *reinterpret_cast<uint4*>(tmp);
}

// ---------------- fused GEMM: h1 = relu(x@W1+b1); h2 = h1@W2+b2 ----------------
// grid (ceil(N/128), 2), 256 threads. blockIdx.y = branch.
// LDS 34816 B union: K-loop { As 16K swizzled | Bs 16K swizzled } ; epilogue Hs [128][136] bf16.
// Epilogue 2 seeds propagation state in channel-contiguous [N][32] layout:
//   ybf[node*32 + br*16 + m16] = bf16(dis[node]*h2),  hid[...] = temp[0]*h2 (f32)

__global__ __launch_bounds__(256, 4) void k_gemm(
    const unsigned short* __restrict__ xbf,
    const unsigned short* __restrict__ W1Tl, const float* __restrict__ b1l,
    const float* __restrict__ W2l, const float* __restrict__ b2l, const float* __restrict__ tl,
    const unsigned short* __restrict__ W1Tg, const float* __restrict__ b1g,
    const float* __restrict__ W2g, const float* __restrict__ b2g, const float* __restrict__ tg,
    const float* __restrict__ dis,
    float* __restrict__ h1l, float* __restrict__ h1g,
    unsigned short* __restrict__ y0, float* __restrict__ hidb, int nNode)
{
    const int br = blockIdx.y;
    const unsigned short* w1t = br ? W1Tg : W1Tl;
    const float* B1 = br ? b1g : b1l;
    const float* W2 = br ? W2g : W2l;
    const float* B2 = br ? b2g : b2l;
    const float* tp = br ? tg : tl;
    float* h1 = br ? h1g : h1l;

    __shared__ __align__(16) unsigned short sm[17408];   // 34816 B
    unsigned short* As = sm;            // slots 0..1023   (rows 0..127 x 8 slots)
    unsigned short* Bs = sm + 8192;     // slots 0..1023
    unsigned short* Hs = sm;            // [128][136] epilogue

    const int t = threadIdx.x;
    const int lane = t & 63;
    const int w = t >> 6;
    const int row0 = blockIdx.x * 128;

    f32x4 acc[2][8];
    for (int i = 0; i < 2; i++)
        for (int j = 0; j < 8; j++)
            acc[i][j] = f32x4{0.f, 0.f, 0.f, 0.f};

    const int m16 = lane & 15;
    const int q = lane >> 4;

    for (int k0 = 0; k0 < F_IN; k0 += 64) {
        #pragma unroll
        for (int j = 0; j < 4; j++) {
            int S0 = w * 256 + j * 64;
            int S = S0 + lane;
            int row = S >> 3;
            int cb = (S & 7) ^ (row & 7);
            dma16(&xbf[(size_t)(row0 + row) * F_IN + k0 + cb * 8], &As[(size_t)S0 * 8]);
        }
        #pragma unroll
        for (int j = 0; j < 4; j++) {
            int S0 = w * 256 + j * 64;
            int S = S0 + lane;
            int n = S >> 3;
            int cb = (S & 7) ^ (n & 7);
            dma16(&w1t[(size_t)n * F_IN + k0 + cb * 8], &Bs[(size_t)S0 * 8]);
        }
        __syncthreads();

        #pragma unroll
        for (int ksub = 0; ksub < 2; ksub++) {
            bf16x8 bf[8];
            #pragma unroll
            for (int ns = 0; ns < 8; ns++) {
                int n = ns * 16 + m16;
                int slot = n * 8 + ((ksub * 4 + q) ^ (n & 7));
                bf[ns] = ld_bf8(&Bs[slot * 8]);
            }
            bf16x8 af[2];
            #pragma unroll
            for (int ms = 0; ms < 2; ms++) {
                int row = w * 32 + ms * 16 + m16;
                int slot = row * 8 + ((ksub * 4 + q) ^ (row & 7));
                af[ms] = ld_bf8(&As[slot * 8]);
            }
            #pragma unroll
            for (int ns = 0; ns < 8; ns++)
                #pragma unroll
                for (int ms = 0; ms < 2; ms++)
                    acc[ms][ns] = __builtin_amdgcn_mfma_f32_16x16x32_bf16(af[ms], bf[ns], acc[ms][ns], 0, 0, 0);
        }
        __syncthreads();
    }

    // epilogue 1: h1 = relu(acc + b1); write global + stash bf16 in LDS
    #pragma unroll
    for (int ms = 0; ms < 2; ms++) {
        #pragma unroll
        for (int ns = 0; ns < 8; ns++) {
            int n = ns * 16 + m16;
            float bias = B1[n];
            #pragma unroll
            for (int r = 0; r < 4; r++) {
                int m = w * 32 + ms * 16 + q * 4 + r;
                float v = acc[ms][ns][r] + bias;
                v = v > 0.f ? v : 0.f;
                Hs[m * 136 + n] = f2bf(v);
                int node = row0 + m;
                if (node < nNode) h1[(size_t)node * HDIM + n] = v;
            }
        }
    }
    __syncthreads();

    // epilogue 2: h2 = h1 @ W2 + b2 via MFMA (N=16); seed y0 (bf16) + hid (f32).
    {
        float t0 = tp[0];
        float bias = B2[m16];
        #pragma unroll
        for (int mi = 0; mi < 2; mi++) {
            int mt = w * 2 + mi;
            f32x4 acc2 = f32x4{bias, bias, bias, bias};
            #pragma unroll
            for (int kb = 0; kb < 4; kb++) {
                bf16x8 hf = ld_bf8(&Hs[(mt * 16 + m16) * 136 + kb * 32 + q * 8]);
                unsigned short wtmp[8];
                #pragma unroll
                for (int j = 0; j < 8; j++)
                    wtmp[j] = f2bf(W2[(size_t)(kb * 32 + q * 8 + j) * CDIM + m16]);
                bf16x8 wf = ld_bf8(wtmp);
                acc2 = __builtin_amdgcn_mfma_f32_16x16x32_bf16(hf, wf, acc2, 0, 0, 0);
            }
            #pragma unroll
            for (int r = 0; r < 4; r++) {
                int node = row0 + mt * 16 + q * 4 + r;
                if (node < nNode) {
                    size_t idx = (size_t)node * 32 + (size_t)br * 16 + m16;
                    float val = acc2[r];
                    y0[idx] = f2bf(dis[node] * val);
                    hidb[idx] = t0 * val;
                }
            }
        }
    }
}

// ---------------- propagation hop: 8 lanes/node x 4 bf16 channels ----------------
// block 256 = 32 nodes; the 8 lanes of a node read CONSECUTIVE 8 B of each
// gathered source row (64 B/row, coalesced); edge index fetched once per lane-group.
// Exchange y is bf16 [N][32]; accumulation is f32; hid stays f32.
// y = dis*x representation: x' = d*(sum_src y[src] + y[v]); y' = bf16(d*x').
// Last hop fuses hid finalization + log_softmax (classes of a branch live in
// 4 adjacent lanes; LSE via two __shfl_xor).

__global__ __launch_bounds__(256) void k_hop3(
    const unsigned short* __restrict__ yin, unsigned short* __restrict__ yout,
    float* __restrict__ hidb, const int* __restrict__ srcs,
    const int* __restrict__ offs, const int* __restrict__ cnt,
    const float* __restrict__ dis,
    const float* __restrict__ tl, const float* __restrict__ tg,
    float* __restrict__ h2l, float* __restrict__ pl,
    float* __restrict__ h2g, float* __restrict__ pg,
    int hop, int N, int last)
{
    int t = threadIdx.x;
    int v = blockIdx.x * 32 + (t >> 3);
    int s = t & 7;
    int c4 = s * 4;
    if (v >= N) return;
    int off = offs[v];
    int m = cnt[v];
    float d = dis[v];
    size_t vbase = (size_t)v * 32 + c4;
    float4 acc = bf4_to_f4(*reinterpret_cast<const uint2*>(yin + vbase));  // self y[v]
    const int* ep = srcs + off;
    int i = 0;
    for (; i + 8 <= m; i += 8) {
        int u[8];
        #pragma unroll
        for (int j = 0; j < 8; j++) u[j] = ep[i + j];
        uint2 xs[8];
        #pragma unroll
        for (int j = 0; j < 8; j++)
            xs[j] = *reinterpret_cast<const uint2*>(yin + (size_t)u[j] * 32 + c4);
        #pragma unroll
        for (int j = 0; j < 8; j++) {
            float4 f = bf4_to_f4(xs[j]);
            acc.x += f.x; acc.y += f.y; acc.z += f.z; acc.w += f.w;
        }
    }
    for (; i < m; i++) {
        float4 f = bf4_to_f4(*reinterpret_cast<const uint2*>(yin + (size_t)ep[i] * 32 + c4));
        acc.x += f.x; acc.y += f.y; acc.z += f.z; acc.w += f.w;
    }
    float4 xn = make_float4(d * acc.x, d * acc.y, d * acc.z, d * acc.w);
    float gamma = (s < 4 ? tl : tg)[hop];
    float4 h = *reinterpret_cast<const float4*>(hidb + vbase);
    h.x = fmaf(gamma, xn.x, h.x);
    h.y = fmaf(gamma, xn.y, h.y);
    h.z = fmaf(gamma, xn.z, h.z);
    h.w = fmaf(gamma, xn.w, h.w);
    if (!last) {
        *reinterpret_cast<float4*>(hidb + vbase) = h;
        *reinterpret_cast<uint2*>(yout + vbase) =
            f4_to_bf4(make_float4(d * xn.x, d * xn.y, d * xn.z, d * xn.w));
    } else {
        // fused log_softmax over this branch's 16 classes (4 adjacent lanes)
        float mloc = fmaxf(fmaxf(h.x, h.y), fmaxf(h.z, h.w));
        mloc = fmaxf(mloc, __shfl_xor(mloc, 1));
        mloc = fmaxf(mloc, __shfl_xor(mloc, 2));
        float sl = __expf(h.x - mloc) + __expf(h.y - mloc) +
                   __expf(h.z - mloc) + __expf(h.w - mloc);
        sl += __shfl_xor(sl, 1);
        sl += __shfl_xor(sl, 2);
        float lse = mloc + __logf(sl);
        float* h2 = s < 4 ? h2l : h2g;
        float* pp = s < 4 ? pl : pg;
        size_t ob = (size_t)v * 16 + (size_t)(s & 3) * 4;
        *reinterpret_cast<float4*>(h2 + ob) = h;
        *reinterpret_cast<float4*>(pp + ob) =
            make_float4(h.x - lse, h.y - lse, h.z - lse, h.w - lse);
    }
}

// ---------------- launch ----------------

extern "C" void kernel_launch(void* const* d_in, const int* in_sizes, int n_in,
                              void* d_out, int out_size, void* d_ws, size_t ws_size,
                              hipStream_t stream)
{
    const float* x   = (const float*)d_in[0];
    const int*   eidx= (const int*)d_in[1];
    const float* W1l = (const float*)d_in[2];
    const float* b1l = (const float*)d_in[3];
    const float* W2l = (const float*)d_in[4];
    const float* b2l = (const float*)d_in[5];
    const float* tl  = (const float*)d_in[6];
    const float* W1g = (const float*)d_in[7];
    const float* b1g = (const float*)d_in[8];
    const float* W2g = (const float*)d_in[9];
    const float* b2g = (const float*)d_in[10];
    const float* tg  = (const float*)d_in[11];

    const int N = in_sizes[0] / F_IN;
    const int E = in_sizes[1] / 2;

    float* out = (float*)d_out;
    float* h1l = out;
    float* h2l = h1l + (size_t)N * HDIM;
    float* pl  = h2l + (size_t)N * CDIM;
    float* h1g = pl  + (size_t)N * CDIM;
    float* h2g = h1g + (size_t)N * HDIM;
    float* pg  = h2g + (size_t)N * CDIM;

    char* ws = (char*)d_ws;
    auto alloc = [&](size_t bytes) -> char* {
        char* p = ws;
        ws += (bytes + 1023) & ~(size_t)1023;
        return p;
    };
    int*   cnt      = (int*)alloc((size_t)N * 4);
    int*   offs     = (int*)alloc((size_t)N * 4);
    int*   ccnt     = (int*)alloc((size_t)(NBMAX + 1) * 4);
    int*   coffs    = (int*)alloc((size_t)(NBMAX + 1) * 4);
    int*   ccur     = (int*)alloc((size_t)NBMAX * CSTR * 4);
    float* dis      = (float*)alloc((size_t)N * 4);
    int*   srcs     = (int*)alloc((size_t)E * 4);
    unsigned short* yA = (unsigned short*)alloc((size_t)N * 32 * 2);  // [N][32] bf16
    unsigned short* yB = (unsigned short*)alloc((size_t)N * 32 * 2);
    float* hidb     = (float*)alloc((size_t)N * 32 * 4);
    unsigned short* W1Tl = (unsigned short*)alloc((size_t)HDIM * F_IN * 2);
    unsigned short* W1Tg = (unsigned short*)alloc((size_t)HDIM * F_IN * 2);
    unsigned short* xbf  = (unsigned short*)alloc((size_t)(N + 256) * F_IN * 2);
    // coarse-partitioned (row,col) edges alias xbf: dead before k_xbf runs (same stream)
    uint2* cedges = (uint2*)xbf;

    hipMemsetAsync(ccnt, 0, (size_t)(NBMAX + 1) * 4, stream);

    int nbuk = (N + 255) / 256;

    k_ccount<<<(E + CH2 - 1) / CH2, 256, 0, stream>>>(eidx, ccnt, E);
    k_cscan<<<1, 256, 0, stream>>>(ccnt, coffs, ccur, nbuk);
    k_part<<<(E + CHUNK - 1) / CHUNK, 256, 0, stream>>>(eidx, ccur, cedges, E);
    k_fineA<<<nbuk, 256, 0, stream>>>(cedges, coffs, cnt, dis, offs, N);
    k_fineB<<<nbuk, 256, 0, stream>>>(cedges, coffs, offs, srcs, N);

    k_xbf<<<(int)(((size_t)N * F_IN) / 2048), 256, 0, stream>>>(x, xbf);
    dim3 gw(32, 2);
    k_w1t<<<gw, 256, 0, stream>>>(W1l, W1g, W1Tl, W1Tg);

    dim3 gg((N + 127) / 128, 2);
    k_gemm<<<gg, 256, 0, stream>>>(xbf, W1Tl, b1l, W2l, b2l, tl,
                                   W1Tg, b1g, W2g, b2g, tg, dis,
                                   h1l, h1g, yA, hidb, N);

    int gh = (N + 31) / 32;
    unsigned short* a = yA;
    unsigned short* b = yB;
    for (int k = 1; k <= KHOPS; k++) {
        k_hop3<<<gh, 256, 0, stream>>>(a, b, hidb, srcs, offs, cnt, dis,
                                       tl, tg, h2l, pl, h2g, pg, k, N, k == KHOPS);
        unsigned short* tmp = a; a = b; b = tmp;
    }
}